// Round 4
// baseline (480.702 us; speedup 1.0000x reference)
//
#include <hip/hip_runtime.h>

// PadWithin PROBE round: same output as always (out[b,c,2i,2j]=in[b,c,i,j],
// rest zero), but the single dispatch performs the full output stream FOUR
// times (idempotent re-writes, separated by compiler memory barriers so the
// passes cannot be elided). Purpose: make this dispatch the longest in the
// timed region (> the 165-170 us poison fills) so its OWN rocprof counters
// (hbm_gbps / FETCH_SIZE / WRITE_SIZE) appear in the top-5 for the first
// time. Pre-registered predictions:
//   near-roofline kernel: ~200-230 us, WRITE ~1.05e6 KB, hbm_gbps ~6000
//   kernel-internal wall: ~540-570 us, hbm_gbps ~2400
// Next round reverts to the single-pass kernel.

#define N4 16777216u   // output float4 count: 16*64*256*256/4

typedef float f2 __attribute__((ext_vector_type(2)));
typedef float f4 __attribute__((ext_vector_type(4)));

__global__ __launch_bounds__(256) void pad_probe_kernel(
    const float* __restrict__ in, float* __restrict__ out) {
    const unsigned tid    = blockIdx.x * blockDim.x + threadIdx.x;
    const unsigned stride = gridDim.x * blockDim.x;   // 524288

    #pragma unroll 1
    for (unsigned r = 0; r < 4; ++r) {
        for (unsigned v = tid; v < N4; v += stride) {
            unsigned col4 = v & 63u;   // float4 index within output row
            unsigned row  = v >> 6;    // global output row
            unsigned oh   = row & 255u;
            unsigned bc   = row >> 8;

            f4 val = {0.f, 0.f, 0.f, 0.f};
            if (!(oh & 1u)) {
                const f2* irow =
                    (const f2*)(in + ((size_t)bc * 128 + (oh >> 1)) * 128);
                f2 x = irow[col4];
                val = (f4){x.x, 0.f, x.y, 0.f};
            }
            ((f4*)out)[v] = val;
        }
        // Prevent cross-pass dead-store elimination; passes must each stream.
        asm volatile("" ::: "memory");
    }
}

extern "C" void kernel_launch(void* const* d_in, const int* in_sizes, int n_in,
                              void* d_out, int out_size, void* d_ws, size_t ws_size,
                              hipStream_t stream) {
    const float* feats = (const float*)d_in[0];
    float* out = (float*)d_out;
    dim3 block(256);
    dim3 grid(2048);   // 524288 threads; 32 f4/thread/pass, no tail
    pad_probe_kernel<<<grid, block, 0, stream>>>(feats, out);
}

// Round 6
// 315.176 us; speedup vs baseline: 1.5252x; 1.5252x over previous
//
#include <hip/hip_runtime.h>

// PadWithin: out[b,c,2i,2j] = feats[b,c,i,j], all other entries zero.
// feats: (16,64,128,128) fp32 -> out: (16,64,256,256) fp32.
//
// Round-4 probe measured the kernel for the first time: 62 us/pass,
// 4.85 TB/s (60% peak), WRITE exactly 268 MB/pass (full-line stores, no
// RMW), input L3-resident (FETCH ~33 MB/pass). Fill on the same buffer:
// 6.4 TB/s. Diagnosis: load->store DEPENDENCY starves the store pipe
// (VALUBusy 9%, waves parked in s_waitcnt on the f2 load before each
// even-row store). R3's zero-pass corroborates: load-free stores ran at
// fill-class BW (469 MB in ~80 us aggregate).
//
// Fix: decouple. Per wave: 8 consecutive row-pairs (16 KiB contiguous out).
//   1) issue 8 independent f2 loads (8 outstanding),
//   2) store 8 odd-row zero f4s (no data dependency -> flow immediately),
//   3) store 8 even-row data f4s as loads retire (vmcnt pipeline).
// All accesses stay perfectly coalesced (512 B/wave loads, 1 KiB/wave stores).

#define IN_W   128
#define PAIRS  (16 * 64 * 128)   // B*C*IN_H = 131072 row-pairs
#define P      8                 // row-pairs per wave

typedef float f2 __attribute__((ext_vector_type(2)));
typedef float f4 __attribute__((ext_vector_type(4)));

__global__ __launch_bounds__(256) void pad_within_kernel(
    const float* __restrict__ in, float* __restrict__ out) {
    const unsigned lane = threadIdx.x & 63u;
    const unsigned wid  = (blockIdx.x * blockDim.x + threadIdx.x) >> 6;
    const unsigned p0   = wid * P;            // first row-pair of this wave

    const f2* irow  = (const f2*)(in  + (size_t)p0 * IN_W) + lane;  // 64 f2/row
    f4*       opair = (f4*)      (out + (size_t)p0 * 512)  + lane;  // 128 f4/pair

    // 1) all loads issued back-to-back: 8 outstanding, no dependent use yet
    f2 x[P];
    #pragma unroll
    for (int k = 0; k < P; ++k) x[k] = irow[(size_t)k * 64];

    // 2) zero rows: depend on nothing, stream while loads are in flight
    const f4 zero = {0.f, 0.f, 0.f, 0.f};
    #pragma unroll
    for (int k = 0; k < P; ++k) opair[(size_t)k * 128 + 64] = zero;

    // 3) data rows: drain loads oldest-first (compiler emits vmcnt(N) ladder)
    #pragma unroll
    for (int k = 0; k < P; ++k)
        opair[(size_t)k * 128] = (f4){x[k].x, 0.f, x[k].y, 0.f};
}

extern "C" void kernel_launch(void* const* d_in, const int* in_sizes, int n_in,
                              void* d_out, int out_size, void* d_ws, size_t ws_size,
                              hipStream_t stream) {
    const float* feats = (const float*)d_in[0];
    float* out = (float*)d_out;
    // 131072 pairs / 8 per wave = 16384 waves = 4096 blocks of 256. No tail.
    dim3 block(256);
    dim3 grid(PAIRS / P / 4);
    pad_within_kernel<<<grid, block, 0, stream>>>(feats, out);
}

// Round 7
// 297.308 us; speedup vs baseline: 1.6168x; 1.0601x over previous
//
#include <hip/hip_runtime.h>

// PadWithin: out[b,c,2i,2j] = feats[b,c,i,j], all other entries zero.
// feats: (16,64,128,128) fp32 -> out: (16,64,256,256) fp32.
//
// Session accounting (closed via R4 probe): timed region = poison fill
// (~167 us, uncontrollable) + hidden reset dispatches (~65 us, measured as
// R4 residual, uncontrollable) + this kernel. Kernel steady state is
// 4.85 TB/s across ALL structures tried (one-shot / persistent / decoupled
// / two-pass), vs 6.4 TB/s for read-free fills on the same buffer.
// R6 killed the load-latency theory (explicit 8-deep decoupling was
// neutral-to-worse). Surviving theory: READ-stream L2 pollution — input
// reads allocate in per-XCD L2, evicting dirty store lines and breaking up
// the write burst stream. Lever: NONTEMPORAL LOADS ONLY (R1 tested nt on
// both sides, which confounds: nt stores forfeit write combining).
//
// Structure: one wave per input row = output row-pair (2 KiB contiguous):
//   lane: nt-load f2 from input row; store zero f4 into odd row
//   (independent -> issues during load flight); store {x,0,y,0} into even
//   row. Both store instructions are dense 1 KiB/wave. One dispatch,
//   8.4M threads (half of R0), no loops.

#define IN_W 128

typedef float f2 __attribute__((ext_vector_type(2)));
typedef float f4 __attribute__((ext_vector_type(4)));

__global__ __launch_bounds__(256) void pad_within_kernel(
    const float* __restrict__ in, float* __restrict__ out) {
    const unsigned lane = threadIdx.x & 63u;
    const unsigned wid  = (blockIdx.x * blockDim.x + threadIdx.x) >> 6;  // row-pair

    const f2* irow  = (const f2*)(in + (size_t)wid * IN_W) + lane;   // 512 B/wave
    f4*       opair = (f4*)(out + (size_t)wid * 512) + lane;         // 2 KiB/pair

    // nt load: bypass L2 allocation (input is L3-resident; never re-read)
    f2 x = __builtin_nontemporal_load(irow);

    // odd output row: no dependency -> store pipe stays busy during load
    opair[64] = (f4){0.f, 0.f, 0.f, 0.f};

    // even output row: {x,0,y,0} once the load retires
    opair[0] = (f4){x.x, 0.f, x.y, 0.f};
}

extern "C" void kernel_launch(void* const* d_in, const int* in_sizes, int n_in,
                              void* d_out, int out_size, void* d_ws, size_t ws_size,
                              hipStream_t stream) {
    const float* feats = (const float*)d_in[0];
    float* out = (float*)d_out;
    // 16*64*128 = 131072 row-pairs = 131072 waves = 32768 blocks of 256.
    dim3 block(256);
    dim3 grid(32768);
    pad_within_kernel<<<grid, block, 0, stream>>>(feats, out);
}